// Round 11
// baseline (139.186 us; speedup 1.0000x reference)
//
#include <hip/hip_runtime.h>

#define NT 10          // trees
#define NL 16          // leaves per tree
#define NN 31          // nodes per tree
#define DD 256         // hidden dim
#define NB 4096
#define NSB 320        // scatter blocks (128 out-rows each)

// Per-block private launch-generation counters (zero-init at module load;
// __device__ space survives ws poison). Each block reads+bumps ONLY its own
// word at entry (read-before-bump) => G = #completed launches, identical
// across all blocks of a launch, dispatch-order- and graph-replay-safe.
// tag = G+1 (1,2,3,...) can never equal ws-poison 0xAAAAAAAA.
__device__ unsigned g_gen[NT * 16];    // treelstm blocks
__device__ unsigned g_sgen[NSB];       // scatter blocks

__device__ __forceinline__ float sigf(float x)   { return 1.0f / (1.0f + __expf(-x)); }
__device__ __forceinline__ float tanh_f(float x) { return 2.0f / (1.0f + __expf(-2.0f*x)) - 1.0f; }

// Gen-tagged word publish/poll (proven R9/R10): datum + readiness in ONE
// aligned 8-byte atomic word => no flag round, no fences; sync cost = one
// store->load visibility hop, per-word skew absorption.
__device__ __forceinline__ void pub64(unsigned long long* p, unsigned tag, float v) {
    union { float f; unsigned u; } c; c.f = v;
    __hip_atomic_store(p, ((unsigned long long)tag << 32) | c.u,
                       __ATOMIC_RELAXED, __HIP_MEMORY_SCOPE_AGENT);
}
__device__ __forceinline__ unsigned long long ld64(const unsigned long long* p) {
    return __hip_atomic_load(p, __ATOMIC_RELAXED, __HIP_MEMORY_SCOPE_AGENT);
}
__device__ __forceinline__ float payload(unsigned long long w) {
    union { unsigned u; float f; } c; c.u = (unsigned)w; return c.f;
}

// ---------------------------------------------------------------------------
// ONE kernel, 480 blocks x 256 threads, __launch_bounds__(256,2):
//   blocks   0..159 : tree-LSTM (R10 body; t = bid>>4, dt = bid&15);
//                     h4 now published as gen-tagged words into hx4.
//   blocks 160..479 : scatter (sb = bid-160, 128 out-rows each): stage cross
//                     + argmax DURING the LSTM, then tag-polled h4 gather ->
//                     40MB coalesced out write starts as h4 words land.
// Co-residency: LDS 57.3KB -> 2 blocks/CU; 480 <= 512 slots, so all blocks
// resident under any dispatch order. Scatter depends only on treelstm words.
// ---------------------------------------------------------------------------
__global__ __launch_bounds__(256, 2) void k_fused(
    const float* __restrict__ cross, const float* __restrict__ emb,
    const float* __restrict__ Wih,   const float* __restrict__ Whh,
    const float* __restrict__ bih,   const float* __restrict__ bhh,
    unsigned long long* __restrict__ hx0, unsigned long long* __restrict__ hx1,
    unsigned long long* __restrict__ hx2, unsigned long long* __restrict__ hx3,
    unsigned long long* __restrict__ hx4,
    float* __restrict__ out)
{
    __shared__ float smem[14336];      // union: treelstm 14336 f / scatter 2176 f
    __shared__ unsigned stag;
    const int tid = threadIdx.x;
    const int bid = blockIdx.x;

    if (bid < 160) {
        // ================= TREE-LSTM (R10 body) =================
        float* es   = smem;            // 31*256
        float* ps   = smem + 7936;     // 8*256
        float* xsl  = smem + 9984;     // 31*64
        float* hs   = smem + 11968;    // 8*256
        float* cbuf = smem + 14016;    // 2*128
        float* bsl  = smem + 14272;    // 64
        float4* es4 = (float4*)es;

        const int t    = bid >> 4;
        const int dt   = bid & 15;
        const int kq   = tid >> 6;     // reduction quarter
        const int w    = tid & 63;     // owned gate-row within tile
        const int gate = w >> 4;
        const int col  = w & 15;
        const int grow = gate * DD + dt * 16 + col;

        if (tid == 0) {
            unsigned G = __hip_atomic_load(&g_gen[t * 16 + dt],
                __ATOMIC_RELAXED, __HIP_MEMORY_SCOPE_AGENT);
            __hip_atomic_store(&g_gen[t * 16 + dt], G + 1u,
                __ATOMIC_RELAXED, __HIP_MEMORY_SCOPE_AGENT);
            stag = G + 1u;
        }
        if (tid < 64) {
            int g2 = tid >> 4, c3 = tid & 15;
            int r2 = g2 * DD + dt * 16 + c3;
            bsl[tid] = bih[r2] + bhh[r2];
        }

        // W_ih + W_hh quarter-rows -> registers (stationary)
        const float4* Wi4 = (const float4*)Wih + (size_t)grow * 64 + kq * 16;
        const float4* Wh4 = (const float4*)Whh + (size_t)grow * 64 + kq * 16;
        float4 wih[16], whh[16];
        #pragma unroll
        for (int j = 0; j < 16; ++j) { wih[j] = Wi4[j]; whh[j] = Wh4[j]; }

        // emb tree rows -> LDS
        const float4* emb4 = (const float4*)emb + (size_t)t * NN * 64;
        #pragma unroll
        for (int r = 0; r < 8; ++r) {
            int idx = tid + 256 * r;
            if (idx < NN * 64) es4[idx] = emb4[idx];
        }
        __syncthreads();
        const unsigned tag = stag;

        // xproj batch [n0, n0+nn): same fmaf chain / fold order as R9/R10.
        auto xbatch = [&](int n0, int nn) {
            __syncthreads();           // prior epilogue may still read ps
            float acc[8];
            #pragma unroll
            for (int m = 0; m < 8; ++m) acc[m] = 0.f;
            #pragma unroll
            for (int j = 0; j < 16; ++j) {
                float4 wv = wih[j];
                #pragma unroll
                for (int m = 0; m < 8; ++m) {
                    if (m < nn) {
                        float4 h = es4[(n0 + m) * 64 + kq * 16 + j];
                        acc[m] = fmaf(wv.x, h.x, fmaf(wv.y, h.y,
                                 fmaf(wv.z, h.z, fmaf(wv.w, h.w, acc[m]))));
                    }
                }
            }
            #pragma unroll
            for (int m = 0; m < 8; ++m)
                if (m < nn) ps[m * DD + kq * 64 + w] = acc[m];
            __syncthreads();
            #pragma unroll
            for (int rep = 0; rep < 2; ++rep) {
                int idx = tid + 256 * rep;       // 0..511
                if (idx < nn * 64) {
                    int m = idx >> 6, w2 = idx & 63;
                    xsl[(n0 + m) * 64 + w2] =
                          ps[m * DD +   0 + w2] + ps[m * DD +  64 + w2]
                        + ps[m * DD + 128 + w2] + ps[m * DD + 192 + w2] + bsl[w2];
                }
            }
            __syncthreads();
        };

        // node 0 only, then root: publish h0 ASAP
        xbatch(0, 1);
        if (tid < 16) {
            float xi  = xsl[ 0 + tid];
            float xgg = xsl[32 + tid];
            float xo  = xsl[48 + tid];
            float c0 = sigf(xi) * tanh_f(xgg);    // h(-1)=c(-1)=0
            float h0 = sigf(xo) * tanh_f(c0);
            cbuf[tid] = c0;
            pub64(hx0 + (size_t)t * DD + dt * 16 + tid, tag, h0);
        }

        // deferred work while h0 propagates
        xbatch(1, 6);                  // nodes 1..6 (steps 1-2 children)

        // stage full h0
        {
            const unsigned long long* src = hx0 + (size_t)t * DD;
            unsigned long long v = ld64(src + tid);
            while ((unsigned)(v >> 32) != tag) {
                __builtin_amdgcn_s_sleep(1);
                v = ld64(src + tid);
            }
            hs[tid] = payload(v);
        }
        __syncthreads();

        const unsigned long long* hin[3] = { hx1, hx2, hx3 };
        unsigned long long* hout[3] = { hx1, hx2, hx3 };

        #pragma unroll
        for (int s = 1; s <= 4; ++s) {
            const int L = 1 << (s - 1);          // input rows per tree

            if (s > 1) {
                const unsigned long long* src = hin[s - 2] + (size_t)t * L * DD;
                unsigned long long v[8];
                #pragma unroll
                for (int r = 0; r < L; ++r) v[r] = ld64(src + tid + 256 * r);
                #pragma unroll
                for (int r = 0; r < L; ++r) {
                    while ((unsigned)(v[r] >> 32) != tag) {
                        __builtin_amdgcn_s_sleep(1);
                        v[r] = ld64(src + tid + 256 * r);
                    }
                    hs[tid + 256 * r] = payload(v[r]);
                }
                __syncthreads();
            }

            // GEMM: acc[p] = <W_hh[grow] quarter kq, h[p] quarter kq>
            const float4* hs4 = (const float4*)hs;
            float acc[8];
            #pragma unroll
            for (int p = 0; p < 8; ++p) acc[p] = 0.f;
            #pragma unroll
            for (int j = 0; j < 16; ++j) {
                float4 wv = whh[j];
                #pragma unroll
                for (int p = 0; p < L; ++p) {
                    float4 h = hs4[p * 64 + kq * 16 + j];  // uniform broadcast
                    acc[p] = fmaf(wv.x, h.x, fmaf(wv.y, h.y,
                             fmaf(wv.z, h.z, fmaf(wv.w, h.w, acc[p]))));
                }
            }
            #pragma unroll
            for (int p = 0; p < L; ++p) ps[p * DD + kq * 64 + w] = acc[p];
            __syncthreads();

            // Epilogue: parent p spawns children q=2p,2p+1; publish at once
            if (tid < 32 * L) {
                const int p  = tid >> 5;
                const int c2 = tid & 15;
                const int q  = tid >> 4;         // child prefix, 0..2L-1
                float g0 = 0.f, g1 = 0.f, g2 = 0.f, g3 = 0.f;
                #pragma unroll
                for (int k = 0; k < 4; ++k) {
                    const float* pp = ps + p * DD + k * 64;
                    g0 += pp[ 0 + c2]; g1 += pp[16 + c2];
                    g2 += pp[32 + c2]; g3 += pp[48 + c2];
                }
                const int node = (1 << s) - 1 + q;
                const float* xp = xsl + node * 64;
                float gi = g0 + xp[ 0 + c2];
                float gf = g1 + xp[16 + c2];
                float gg = g2 + xp[32 + c2];
                float go = g3 + xp[48 + c2];
                float cin = cbuf[((s - 1) & 1) * 128 + p * 16 + c2];
                float cn  = sigf(gf) * cin + sigf(gi) * tanh_f(gg);
                float hn  = sigf(go) * tanh_f(cn);
                if (s < 4) {
                    cbuf[(s & 1) * 128 + q * 16 + c2] = cn;
                    pub64(hout[s - 1] + (size_t)(t * 2 * L + q) * DD
                                      + dt * 16 + c2, tag, hn);
                } else {
                    // gen-tagged h4: scatter blocks poll these words
                    pub64(hx4 + (size_t)(t * NL + q) * DD
                              + dt * 16 + c2, tag, hn);
                }
            }

            // deferred xproj while this step's h propagates to peers
            if (s == 1)      xbatch( 7, 8);      // nodes  7..14 (step 3)
            else if (s == 2) xbatch(15, 8);      // nodes 15..22 (step 4)
            else if (s == 3) xbatch(23, 8);      // nodes 23..30 (step 4)
        }
    } else {
        // ================= SCATTER =================
        float* cls  = smem;            // 128 rows x 16 leaves
        int* leafs  = (int*)(smem + 2048);

        const int sb = bid - 160;
        const size_t r0 = (size_t)sb * 128;

        if (tid == 0) {
            unsigned G = __hip_atomic_load(&g_sgen[sb],
                __ATOMIC_RELAXED, __HIP_MEMORY_SCOPE_AGENT);
            __hip_atomic_store(&g_sgen[sb], G + 1u,
                __ATOMIC_RELAXED, __HIP_MEMORY_SCOPE_AGENT);
            stag = G + 1u;
        }

        // stage cross + argmax — overlaps the whole LSTM phase
        #pragma unroll
        for (int k = 0; k < 8; ++k)
            cls[tid + 256 * k] = cross[r0 * 16 + tid + 256 * k];
        __syncthreads();
        const unsigned tag = stag;
        if (tid < 128) {
            int leaf = 0;
            #pragma unroll
            for (int l = 15; l >= 0; --l)
                if (cls[tid * 16 + l] > 0.5f) leaf = l;
            int r = (int)(r0 + (size_t)tid);
            int b = r / NT;
            int t = r - b * NT;
            leafs[tid] = t * 16 + leaf;
        }
        __syncthreads();

        // tag-polled gather -> 40MB coalesced out write; starts as soon as
        // the needed h4 words land (self-validating per word)
        const int wave = tid >> 6;
        const int lane = tid & 63;
        float4* o4 = (float4*)out;
        #pragma unroll 4
        for (int it = 0; it < 32; ++it) {
            int rr = it * 4 + wave;              // 0..127
            const unsigned long long* hw =
                hx4 + (size_t)leafs[rr] * DD + lane * 4;
            unsigned long long w0 = ld64(hw + 0);
            unsigned long long w1 = ld64(hw + 1);
            unsigned long long w2 = ld64(hw + 2);
            unsigned long long w3 = ld64(hw + 3);
            while ((unsigned)(w0 >> 32) != tag) { __builtin_amdgcn_s_sleep(1); w0 = ld64(hw + 0); }
            while ((unsigned)(w1 >> 32) != tag) { __builtin_amdgcn_s_sleep(1); w1 = ld64(hw + 1); }
            while ((unsigned)(w2 >> 32) != tag) { __builtin_amdgcn_s_sleep(1); w2 = ld64(hw + 2); }
            while ((unsigned)(w3 >> 32) != tag) { __builtin_amdgcn_s_sleep(1); w3 = ld64(hw + 3); }
            float4 f;
            f.x = payload(w0); f.y = payload(w1);
            f.z = payload(w2); f.w = payload(w3);
            o4[(r0 + rr) * 64 + lane] = f;
        }
    }
}

// ---------------------------------------------------------------------------
extern "C" void kernel_launch(void* const* d_in, const int* in_sizes, int n_in,
                              void* d_out, int out_size, void* d_ws, size_t ws_size,
                              hipStream_t stream)
{
    const float* cross = (const float*)d_in[0];
    const float* emb   = (const float*)d_in[1];
    const float* Wih   = (const float*)d_in[2];
    const float* Whh   = (const float*)d_in[3];
    const float* bih   = (const float*)d_in[4];
    const float* bhh   = (const float*)d_in[5];
    float* out = (float*)d_out;

    unsigned long long* hx0 = (unsigned long long*)d_ws;   // 10*256 u64
    unsigned long long* hx1 = hx0 + (size_t)NT * DD;       // 20*256
    unsigned long long* hx2 = hx1 + (size_t)2 * NT * DD;   // 40*256
    unsigned long long* hx3 = hx2 + (size_t)4 * NT * DD;   // 80*256
    unsigned long long* hx4 = hx3 + (size_t)8 * NT * DD;   // 160*256 (tagged)

    hipLaunchKernelGGL(k_fused, dim3(160 + NSB), dim3(256), 0, stream,
                       cross, emb, Wih, Whh, bih, bhh,
                       hx0, hx1, hx2, hx3, hx4, out);
}

// Round 12
// 104.108 us; speedup vs baseline: 1.3369x; 1.3369x over previous
//
#include <hip/hip_runtime.h>

#define NT 10          // trees
#define NL 16          // leaves per tree
#define NN 31          // nodes per tree
#define DD 256         // hidden dim
#define NB 4096

// Per-block private launch-generation counters (zero-init at module load;
// __device__ space survives ws poison). Block (t,dt) alone reads+bumps its
// word at entry: read-before-bump => G = #completed launches, identical
// across all blocks of a launch, dispatch-order- and graph-replay-safe.
// tag = G+1 (1,2,3,...) can never equal ws-poison 0xAAAAAAAA.
__device__ unsigned g_gen[NT * 16];

__device__ __forceinline__ float sigf(float x)   { return 1.0f / (1.0f + __expf(-x)); }
__device__ __forceinline__ float tanh_f(float x) { return 2.0f / (1.0f + __expf(-2.0f*x)) - 1.0f; }

// ---------------------------------------------------------------------------
// MALL-direct exchange (the R12 change). __hip_atomic_* AGENT ops only
// bypass L1 (sc0); they still ack/serve at the local XCD L2, so cross-XCD
// words sit STALE until chance eviction (~7us/round, invariant across R2-R11
// protocol variants). gfx950 global_load/store accept `sc0 sc1`: sc1
// bypasses the L2 and hits the MALL (the true inter-XCD coherence point)
// directly -> one ~1us visibility hop. Datum+tag live in ONE u64, so no
// ordering problem exists (self-validating word, proven R9/R10).
// ---------------------------------------------------------------------------
__device__ __forceinline__ void pub64(unsigned long long* p, unsigned tag, float v) {
    union { float f; unsigned u; } c; c.f = v;
    unsigned long long w = ((unsigned long long)tag << 32) | c.u;
    asm volatile("global_store_dwordx2 %0, %1, off sc0 sc1"
                 :: "v"(p), "v"(w) : "memory");
}
__device__ __forceinline__ unsigned long long ld64(const unsigned long long* p) {
    unsigned long long r;
    asm volatile("global_load_dwordx2 %0, %1, off sc0 sc1\n\t"
                 "s_waitcnt vmcnt(0)"
                 : "=v"(r) : "v"(p) : "memory");
    return r;
}
__device__ __forceinline__ float payload(unsigned long long w) {
    union { unsigned u; float f; } c; c.u = (unsigned)w; return c.f;
}

// ---------------------------------------------------------------------------
// K1: whole tree-LSTM, 160 blocks = 10 trees x 16 d-tiles (R10 structure,
// interleaved xproj schedule):
//   entry -> x[0] -> root+pub(h0) -> x[1..6] -> stage h0 -> s1 -> pub(h1)
//   -> x[7..14] -> stage h1 -> s2 -> pub(h2) -> x[15..22] -> stage h2 -> s3
//   -> pub(h3) -> x[23..30] -> stage h3 -> s4 -> h4 store (launch boundary).
// Math/indices byte-identical to R10; only the exchange ops changed to
// MALL-direct sc0 sc1 asm.
// ---------------------------------------------------------------------------
__global__ __launch_bounds__(256) void k_treelstm(
    const float* __restrict__ emb, const float* __restrict__ Wih,
    const float* __restrict__ Whh, const float* __restrict__ bih,
    const float* __restrict__ bhh,
    unsigned long long* __restrict__ hx0, unsigned long long* __restrict__ hx1,
    unsigned long long* __restrict__ hx2, unsigned long long* __restrict__ hx3,
    float* __restrict__ h4g)
{
    __shared__ float es [NN * DD];     // 31 emb rows (tree-local)
    __shared__ float ps [8 * DD];      // GEMM partials (4 quarters x 64)
    __shared__ float xsl[NN * 64];     // x-gate slices incl. bias
    __shared__ float hs [8 * DD];      // staged input h rows
    __shared__ float cbuf[2 * 128];    // c ping-pong (block's 16 cols)
    __shared__ float bsl[64];
    __shared__ unsigned stag;

    const int tid  = threadIdx.x;
    const int t    = blockIdx.x >> 4;
    const int dt   = blockIdx.x & 15;
    const int kq   = tid >> 6;         // reduction quarter
    const int w    = tid & 63;         // owned gate-row within tile
    const int gate = w >> 4;
    const int col  = w & 15;
    const int grow = gate * DD + dt * 16 + col;

    if (tid == 0) {
        unsigned G = __hip_atomic_load(&g_gen[t * 16 + dt],
            __ATOMIC_RELAXED, __HIP_MEMORY_SCOPE_AGENT);
        __hip_atomic_store(&g_gen[t * 16 + dt], G + 1u,
            __ATOMIC_RELAXED, __HIP_MEMORY_SCOPE_AGENT);
        stag = G + 1u;
    }
    if (tid < 64) {
        int g2 = tid >> 4, c3 = tid & 15;
        int r2 = g2 * DD + dt * 16 + c3;
        bsl[tid] = bih[r2] + bhh[r2];
    }

    // ---- W_ih + W_hh quarter-rows -> registers (stationary)
    const float4* Wi4 = (const float4*)Wih + (size_t)grow * 64 + kq * 16;
    const float4* Wh4 = (const float4*)Whh + (size_t)grow * 64 + kq * 16;
    float4 wih[16], whh[16];
    #pragma unroll
    for (int j = 0; j < 16; ++j) { wih[j] = Wi4[j]; whh[j] = Wh4[j]; }

    // ---- emb tree rows -> LDS
    const float4* emb4 = (const float4*)emb + (size_t)t * NN * 64;
    float4* es4 = (float4*)es;
    #pragma unroll
    for (int r = 0; r < 8; ++r) {
        int idx = tid + 256 * r;                 // 0..2047, need < 1984
        if (idx < NN * 64) es4[idx] = emb4[idx];
    }
    __syncthreads();
    const unsigned tag = stag;

    // xproj batch [n0, n0+nn), nn <= 8: same fmaf chain / fold order as R10.
    auto xbatch = [&](int n0, int nn) {
        __syncthreads();               // prior epilogue may still read ps
        float acc[8];
        #pragma unroll
        for (int m = 0; m < 8; ++m) acc[m] = 0.f;
        #pragma unroll
        for (int j = 0; j < 16; ++j) {
            float4 wv = wih[j];
            #pragma unroll
            for (int m = 0; m < 8; ++m) {
                if (m < nn) {
                    float4 h = es4[(n0 + m) * 64 + kq * 16 + j];
                    acc[m] = fmaf(wv.x, h.x, fmaf(wv.y, h.y,
                             fmaf(wv.z, h.z, fmaf(wv.w, h.w, acc[m]))));
                }
            }
        }
        #pragma unroll
        for (int m = 0; m < 8; ++m)
            if (m < nn) ps[m * DD + kq * 64 + w] = acc[m];
        __syncthreads();
        #pragma unroll
        for (int rep = 0; rep < 2; ++rep) {
            int idx = tid + 256 * rep;           // 0..511
            if (idx < nn * 64) {
                int m = idx >> 6, w2 = idx & 63;
                xsl[(n0 + m) * 64 + w2] =
                      ps[m * DD +   0 + w2] + ps[m * DD +  64 + w2]
                    + ps[m * DD + 128 + w2] + ps[m * DD + 192 + w2] + bsl[w2];
            }
        }
        __syncthreads();
    };

    // ---- node 0 only, then root: publish h0 ASAP
    xbatch(0, 1);
    if (tid < 16) {
        float xi  = xsl[ 0 + tid];
        float xgg = xsl[32 + tid];
        float xo  = xsl[48 + tid];
        float c0 = sigf(xi) * tanh_f(xgg);        // h(-1)=c(-1)=0
        float h0 = sigf(xo) * tanh_f(c0);
        cbuf[tid] = c0;
        pub64(hx0 + (size_t)t * DD + dt * 16 + tid, tag, h0);
    }

    // ---- deferred work while h0 propagates
    xbatch(1, 6);                      // nodes 1..6 (steps 1-2 children)

    // ---- stage full h0
    {
        const unsigned long long* src = hx0 + (size_t)t * DD;
        unsigned long long v = ld64(src + tid);
        while ((unsigned)(v >> 32) != tag) {
            __builtin_amdgcn_s_sleep(1);
            v = ld64(src + tid);
        }
        hs[tid] = payload(v);
    }
    __syncthreads();

    const unsigned long long* hin[3] = { hx1, hx2, hx3 };
    unsigned long long* hout[3] = { hx1, hx2, hx3 };

    #pragma unroll
    for (int s = 1; s <= 4; ++s) {
        const int L = 1 << (s - 1);              // input rows per tree

        if (s > 1) {
            // poll-stage L full rows; per-word self-validating, MALL-direct
            const unsigned long long* src = hin[s - 2] + (size_t)t * L * DD;
            unsigned long long v[8];
            #pragma unroll
            for (int r = 0; r < L; ++r) v[r] = ld64(src + tid + 256 * r);
            #pragma unroll
            for (int r = 0; r < L; ++r) {
                while ((unsigned)(v[r] >> 32) != tag) {
                    __builtin_amdgcn_s_sleep(1);
                    v[r] = ld64(src + tid + 256 * r);
                }
                hs[tid + 256 * r] = payload(v[r]);
            }
            __syncthreads();
        }

        // GEMM: acc[p] = <W_hh[grow] quarter kq, h[p] quarter kq>
        const float4* hs4 = (const float4*)hs;
        float acc[8];
        #pragma unroll
        for (int p = 0; p < 8; ++p) acc[p] = 0.f;
        #pragma unroll
        for (int j = 0; j < 16; ++j) {
            float4 wv = whh[j];
            #pragma unroll
            for (int p = 0; p < L; ++p) {
                float4 h = hs4[p * 64 + kq * 16 + j];    // uniform broadcast
                acc[p] = fmaf(wv.x, h.x, fmaf(wv.y, h.y,
                         fmaf(wv.z, h.z, fmaf(wv.w, h.w, acc[p]))));
            }
        }
        #pragma unroll
        for (int p = 0; p < L; ++p) ps[p * DD + kq * 64 + w] = acc[p];
        __syncthreads();

        // Epilogue: parent p spawns children q=2p,2p+1; publish IMMEDIATELY
        if (tid < 32 * L) {
            const int p  = tid >> 5;
            const int c2 = tid & 15;
            const int q  = tid >> 4;             // child prefix, 0..2L-1
            float g0 = 0.f, g1 = 0.f, g2 = 0.f, g3 = 0.f;
            #pragma unroll
            for (int k = 0; k < 4; ++k) {
                const float* pp = ps + p * DD + k * 64;
                g0 += pp[ 0 + c2]; g1 += pp[16 + c2];
                g2 += pp[32 + c2]; g3 += pp[48 + c2];
            }
            const int node = (1 << s) - 1 + q;
            const float* xp = xsl + node * 64;
            float gi = g0 + xp[ 0 + c2];
            float gf = g1 + xp[16 + c2];
            float gg = g2 + xp[32 + c2];
            float go = g3 + xp[48 + c2];
            float cin = cbuf[((s - 1) & 1) * 128 + p * 16 + c2];
            float cn  = sigf(gf) * cin + sigf(gi) * tanh_f(gg);
            float hn  = sigf(go) * tanh_f(cn);
            if (s < 4) {
                cbuf[(s & 1) * 128 + q * 16 + c2] = cn;
                pub64(hout[s - 1] + (size_t)(t * 2 * L + q) * DD
                                  + dt * 16 + c2, tag, hn);
            } else {
                // launch boundary publishes h4 to the scatter kernel
                h4g[(size_t)(t * NL + q) * DD + dt * 16 + c2] = hn;
            }
        }

        // ---- deferred xproj while this step's h propagates to peers
        if (s == 1)      xbatch( 7, 8);          // nodes  7..14 (step 3)
        else if (s == 2) xbatch(15, 8);          // nodes 15..22 (step 4)
        else if (s == 3) xbatch(23, 8);          // nodes 23..30 (step 4)
    }
}

// ---------------------------------------------------------------------------
// K2: scatter out[b,t,:] = h4[t*16 + argmax(cross[b,t,:]), :]
// One wave per (b,t) row (40960 waves): ballot -> leaf, float4 row copy.
// (Proven R2 version.)
// ---------------------------------------------------------------------------
__global__ __launch_bounds__(256) void k_scatter(
    const float* __restrict__ cross, const float* __restrict__ htab,
    float* __restrict__ out)
{
    const int tid  = threadIdx.x;
    const int wave = tid >> 6;
    const int lane = tid & 63;
    const int r = blockIdx.x * 4 + wave;     // 0..40959 = b*10 + t
    const int b = r / NT;
    const int t = r - b * NT;

    float v = 0.f;
    if (lane < NL) v = cross[(size_t)b * (NT * NL) + t * NL + lane];
    unsigned long long m = __ballot(v > 0.5f);
    int leaf = m ? (int)__builtin_ctzll(m) : 0;
    int p = t * NL + leaf;

    const float4* h4 = (const float4*)htab;
    float4* o4 = (float4*)out;
    o4[(size_t)r * 64 + lane] = h4[(size_t)p * 64 + lane];
}

// ---------------------------------------------------------------------------
extern "C" void kernel_launch(void* const* d_in, const int* in_sizes, int n_in,
                              void* d_out, int out_size, void* d_ws, size_t ws_size,
                              hipStream_t stream)
{
    const float* cross = (const float*)d_in[0];
    const float* emb   = (const float*)d_in[1];
    const float* Wih   = (const float*)d_in[2];
    const float* Whh   = (const float*)d_in[3];
    const float* bih   = (const float*)d_in[4];
    const float* bhh   = (const float*)d_in[5];
    float* out = (float*)d_out;

    unsigned long long* hx0 = (unsigned long long*)d_ws;   // 10*256 u64
    unsigned long long* hx1 = hx0 + (size_t)NT * DD;       // 20*256
    unsigned long long* hx2 = hx1 + (size_t)2 * NT * DD;   // 40*256
    unsigned long long* hx3 = hx2 + (size_t)4 * NT * DD;   // 80*256
    float* h4g = (float*)(hx3 + (size_t)8 * NT * DD);      // 160*256 f32

    hipLaunchKernelGGL(k_treelstm, dim3(160), dim3(256), 0, stream,
                       emb, Wih, Whh, bih, bhh, hx0, hx1, hx2, hx3, h4g);
    hipLaunchKernelGGL(k_scatter, dim3(10240), dim3(256), 0, stream,
                       cross, h4g, out);
}